// Round 11
// baseline (59779.285 us; speedup 1.0000x reference)
//
#include <hip/hip_runtime.h>

#define DI __device__ __forceinline__

using half8 = __attribute__((ext_vector_type(8))) _Float16;
using f32x4 = __attribute__((ext_vector_type(4))) float;
using ull = unsigned long long;

static constexpr int T_ = 256;
static constexpr int B_ = 32;
static constexpr int H_ = 1024;
static constexpr int V_ = 8192;
static constexpr int TPB = 256;
static constexpr int BH = B_ * H_;        // 32768 elems
static constexpr int GX = 4 * H_;         // 4096 gate rows
static constexpr int TC = 8;              // helper chunk (steps)
static constexpr int NCH = T_ / TC;       // 32 chunks
static constexpr int GUARD = 60000;       // sc1 poll cap
static constexpr int FASTG = 4000;        // fast (sc0/L2) poll cap

// ---- device state (re-initialized every launch by init kernel) ----
__device__ _Float16 g_y0loc[(T_ + 1) * BH];         // L0 h chain (XCD0 L2 traffic)
__device__ _Float16 g_y1loc[(T_ + 1) * BH];         // L1 h chain (XCD1 L2 traffic)
__device__ ull g_y0pub[(size_t)(T_ + 1) * BH / 4];  // L0 h published (sc1)
__device__ ull g_ggx[(size_t)T_ * B_ * GX / 4];     // helpers: y0@Wih1^T (no bias)
__device__ _Float16 g_Wt[(size_t)V_ * GX];          // W_ih0^T fp16: [vocab][4H]
__device__ unsigned g_xcdcnt[8 * 32];               // per-XCD election tickets
__device__ unsigned g_heltick[32];                  // global helper ticket
__device__ unsigned g_f0[32 * 32], g_s0[32 * 32];   // L0 slots: fast(plain/L2) + slow(sc1)
__device__ unsigned g_f1[32 * 32], g_s1[32 * 32];   // L1 slots
__device__ unsigned g_l0prog[32];                   // y0pub slots 0..P valid (sc1)
__device__ unsigned g_chunk[NCH * 32];              // helper chunk arrivals (sc1)

__global__ void init_bar_k() {
  const int i = threadIdx.x;   // 1024 threads
  g_f0[i] = 0u; g_s0[i] = 0u; g_f1[i] = 0u; g_s1[i] = 0u;   // 32*32 = 1024 each
  g_chunk[i] = 0u;                                           // NCH*32 = 1024
  if (i < 256) g_xcdcnt[i] = 0u;
  if (i < 32)  { g_l0prog[i] = 0u; g_heltick[i] = 0u; }
}

// ---------------------------------------------------------------------------
// Prepass: W_ih0 (4096 x 8192) f32 -> g_Wt (8192 x 4096) fp16
// ---------------------------------------------------------------------------
__global__ __launch_bounds__(256) void transpose_wih0(const float* __restrict__ in) {
  __shared__ _Float16 t[64][72];
  const int bc = blockIdx.x & 127;
  const int br = blockIdx.x >> 7;
  const int r0 = br * 64, v0 = bc * 64;
  const int tx = threadIdx.x & 15, ty = threadIdx.x >> 4;
#pragma unroll
  for (int it = 0; it < 4; ++it) {
    const int row = ty + it * 16;
    const float4 f = *(const float4*)&in[(size_t)(r0 + row) * V_ + v0 + tx * 4];
    t[tx * 4 + 0][row] = (_Float16)f.x;
    t[tx * 4 + 1][row] = (_Float16)f.y;
    t[tx * 4 + 2][row] = (_Float16)f.z;
    t[tx * 4 + 3][row] = (_Float16)f.w;
  }
  __syncthreads();
#pragma unroll
  for (int it = 0; it < 4; ++it) {
    const int vrow = ty + it * 16;
    union { _Float16 h[4]; ull u; } o;
    o.h[0] = t[vrow][tx * 4 + 0]; o.h[1] = t[vrow][tx * 4 + 1];
    o.h[2] = t[vrow][tx * 4 + 2]; o.h[3] = t[vrow][tx * 4 + 3];
    *(ull*)&g_Wt[(size_t)(v0 + vrow) * GX + r0 + tx * 4] = o.u;
  }
}

// ---------------------------------------------------------------------------
DI unsigned ld_ag(const unsigned* p) { return __hip_atomic_load(p, __ATOMIC_RELAXED, __HIP_MEMORY_SCOPE_AGENT); }
DI void st_ag(unsigned* p, unsigned v) { __hip_atomic_store(p, v, __ATOMIC_RELAXED, __HIP_MEMORY_SCOPE_AGENT); }
DI unsigned add_ag(unsigned* p) { return __hip_atomic_fetch_add(p, 1u, __ATOMIC_RELAXED, __HIP_MEMORY_SCOPE_AGENT); }
DI void st_ag64(ull* p, ull v) { __hip_atomic_store(p, v, __ATOMIC_RELAXED, __HIP_MEMORY_SCOPE_AGENT); }
DI ull ld_ag64(const ull* p) { return __hip_atomic_load(p, __ATOMIC_RELAXED, __HIP_MEMORY_SCOPE_AGENT); }

// L1-bypassing load (reads at the local XCD L2 coherence point, NOT the LLC)
DI unsigned ld_sc0(const unsigned* p) {
  unsigned v;
  asm volatile("global_load_dword %0, %1, off sc0\n\ts_waitcnt vmcnt(0)"
               : "=v"(v) : "v"(p) : "memory");
  return v;
}

DI float sigmf(float v) { return 1.0f / (1.0f + __expf(-v)); }
DI float tanhf_(float v) { return 1.0f - 2.0f / (__expf(2.0f * v) + 1.0f); }

DI half8 load8_cvt(const float* __restrict__ p) {
  const float4* q = (const float4*)p;
  float4 a = q[0], b = q[1];
  half8 r;
  r[0] = (_Float16)a.x; r[1] = (_Float16)a.y; r[2] = (_Float16)a.z; r[3] = (_Float16)a.w;
  r[4] = (_Float16)b.x; r[5] = (_Float16)b.y; r[6] = (_Float16)b.z; r[7] = (_Float16)b.w;
  return r;
}

// Wait for all 32 peers >= r: fast sc0 poll of plain flags (intra-XCD L2),
// sc1 fallback for correctness. Lane 32 optionally polls an sc1 gate.
DI void slot_wait2(unsigned* fast, unsigned* slow, unsigned r,
                   const unsigned* extra, unsigned extraTgt) {
  const int tid = threadIdx.x;
  if (tid < 64) {
    if (tid < 32) {
      const unsigned* pf = &fast[tid * 32];
      int it = 0;
      for (; it < FASTG; ++it) {
        if (ld_sc0(pf) >= r) break;
        __builtin_amdgcn_s_sleep(1);
      }
      if (it >= FASTG) {
        const unsigned* ps = &slow[tid * 32];
        int guard = 0;
        while (ld_ag(ps) < r) {
          __builtin_amdgcn_s_sleep(1);
          if (++guard > GUARD) break;
        }
      }
    } else if (tid == 32 && extra) {
      int guard = 0;
      while (ld_ag(extra) < extraTgt) {
        __builtin_amdgcn_s_sleep(1);
        if (++guard > GUARD) break;
      }
    }
  }
  __syncthreads();
}

// Announce round r: plain write-through store (fast, local L2) + sc1 insurance.
DI void announce(unsigned* fast, unsigned* slow, unsigned rank, unsigned r) {
  *(volatile unsigned*)&fast[rank * 32] = r;
  st_ag(&slow[rank * 32], r);
}

// Stage one 32x1024 fp16 matrix (64KB) global->LDS in MFMA-fragment order:
// dest chunk c = kk*128 + half*64 + lane  holds  h[half*16 + (lane&15)]
// [kk*32 + (lane>>4)*8 .. +8]  -> wave reads are base + lane*16 (conflict-free).
DI void stage_h(_Float16* ldsbase, const _Float16* src, int w) {
  const int lane = (int)(threadIdx.x & 63);
#pragma unroll
  for (int i = 0; i < 16; ++i) {
    const int c = (w * 16 + i) * 64 + lane;          // dest 16B chunk id
    const int kk = c >> 7;
    const int half = (c >> 6) & 1;
    const int l = c & 63;
    const int row = half * 16 + (l & 15);
    const int srcchunk = row * 128 + kk * 4 + (l >> 4);
    __builtin_amdgcn_global_load_lds(
        (const __attribute__((address_space(1))) void*)((const char*)src + (size_t)srcchunk * 16),
        (__attribute__((address_space(3))) void*)((char*)ldsbase + (size_t)(w * 16 + i) * 1024),
        16, 0, 0);
  }
}

// ---------------------------------------------------------------------------
__global__ __launch_bounds__(TPB, 1) void lstm_fused(
    const float* __restrict__ Whh0,
    const float* __restrict__ bih0, const float* __restrict__ bhh0,
    const float* __restrict__ Wih1,
    const float* __restrict__ Whh1,
    const float* __restrict__ bih1, const float* __restrict__ bhh1,
    const int* __restrict__ x,
    const float* __restrict__ Hst,
    const float* __restrict__ Cst,
    float* __restrict__ y1out,
    float* __restrict__ outh,
    float* __restrict__ outc)
{
  const int tid = threadIdx.x;
  const int lane = tid & 63;
  const int w = tid >> 6;

  __shared__ _Float16 stage_s[BH];       // 64 KB
  __shared__ float gates_s[32 * 132];    // 16.5 KB -> ~81KB total -> 1 block/CU
  __shared__ unsigned sh_xcc, sh_rank;

  if (tid == 0) {
    unsigned xc;
    asm volatile("s_getreg_b32 %0, hwreg(HW_REG_XCC_ID)" : "=s"(xc));
    xc &= 7u;
    sh_xcc = xc;
    sh_rank = __hip_atomic_fetch_add(&g_xcdcnt[xc * 32], 1u,
                                     __ATOMIC_RELAXED, __HIP_MEMORY_SCOPE_AGENT);
  }
  __syncthreads();
  const unsigned xcc = sh_xcc;
  const unsigned rank = sh_rank;

  const int kgrp = (lane >> 4) * 8;      // halfs

  // =========================== recurrence role ===========================
  if (xcc <= 1u && rank < 32u) {
    const bool isL1 = (xcc == 1u);
    const int jbase = (int)rank * 32;    // this block's 32 hidden dims
    const float* Whh = isL1 ? Whh1 : Whh0;
    const float* bih = isL1 ? bih1 : bih0;
    const float* bhh = isL1 ? bhh1 : bhh0;
    _Float16* yloc = isL1 ? g_y1loc : g_y0loc;
    unsigned* slotF = isL1 ? g_f1 : g_f0;
    unsigned* slotS = isL1 ? g_s1 : g_s0;

    // W_hh fragments -> VGPRs (wave w == gate w; two 16-dim N-tiles)
    half8 wf0[32], wf1[32];
    {
      const int rw0 = w * H_ + jbase + (lane & 15);
      const int rw1 = rw0 + 16;
#pragma unroll
      for (int kk = 0; kk < 32; ++kk) {
        wf0[kk] = load8_cvt(Whh + (size_t)rw0 * H_ + kk * 32 + kgrp);
        wf1[kk] = load8_cvt(Whh + (size_t)rw1 * H_ + kk * 32 + kgrp);
      }
    }

    const int b = tid >> 3;
    const int d0 = (tid & 7) * 4;
    const int j0 = jbase + d0;

    float bs[4][4];
#pragma unroll
    for (int g = 0; g < 4; ++g)
#pragma unroll
      for (int dd = 0; dd < 4; ++dd)
        bs[g][dd] = bih[g * H_ + j0 + dd] + bhh[g * H_ + j0 + dd];

    float cc[4], hf[4];
    {
      const float4 hi = *(const float4*)&Hst[(isL1 ? BH : 0) + b * H_ + j0];
      const float4 ci = *(const float4*)&Cst[(isL1 ? BH : 0) + b * H_ + j0];
      cc[0] = ci.x; cc[1] = ci.y; cc[2] = ci.z; cc[3] = ci.w;
      hf[0] = hi.x; hf[1] = hi.y; hf[2] = hi.z; hf[3] = hi.w;
    }
    union { _Float16 h[4]; ull u; } pk;
#pragma unroll
    for (int dd = 0; dd < 4; ++dd) pk.h[dd] = (_Float16)hf[dd];
    ull hv_keep = pk.u;
    *(ull*)&yloc[(size_t)b * H_ + j0] = hv_keep;     // slot 0 (plain, local L2)

    __syncthreads();                                  // drain slot-0 stores
    if (tid == 0) announce(slotF, slotS, rank, 1u);

    for (int t = 0; t < T_; ++t) {
      // input-side gates: prefetch BEFORE the wait when legal
      ull gxu[4];
      if (!isL1) {
        const int xv = x[t * B_ + b];
        const _Float16* gp = g_Wt + (size_t)xv * GX + j0;
#pragma unroll
        for (int g = 0; g < 4; ++g) gxu[g] = *(const ull*)(gp + g * H_);
      } else if (t & (TC - 1)) {
        const size_t gbase = (((size_t)t * B_ + b) * GX + j0) >> 2;
#pragma unroll
        for (int g = 0; g < 4; ++g) gxu[g] = ld_ag64(&g_ggx[gbase + (size_t)(g * H_ >> 2)]);
      }

      // ---- wait: all 32 peers at round t+1 (+ chunk gate for L1) ----
      const unsigned r = (unsigned)(t + 1);
      if (isL1 && (t & (TC - 1)) == 0)
        slot_wait2(slotF, slotS, r, &g_chunk[(t / TC) * 32], 128u);
      else
        slot_wait2(slotF, slotS, r, nullptr, 0u);

      if (!isL1) {
        if (rank == 0u && tid == 0 && t >= 1) st_ag(g_l0prog, (unsigned)(t - 1));
        st_ag64(&g_y0pub[((size_t)t * BH + b * H_ + j0) >> 2], hv_keep);
      } else if ((t & (TC - 1)) == 0) {
        const size_t gbase = (((size_t)t * B_ + b) * GX + j0) >> 2;
#pragma unroll
        for (int g = 0; g < 4; ++g) gxu[g] = ld_ag64(&g_ggx[gbase + (size_t)(g * H_ >> 2)]);
      }

      // stage h(t) 64KB -> LDS in fragment order (same-XCD L2 hits)
      stage_h(stage_s, yloc + (size_t)t * BH, w);
      __syncthreads();

      // MFMA: 2 M-tiles x 2 N-tiles x K=1024; conflict-free lane-linear reads
      f32x4 a00 = {0.f,0.f,0.f,0.f}, a01 = {0.f,0.f,0.f,0.f};
      f32x4 a10 = {0.f,0.f,0.f,0.f}, a11 = {0.f,0.f,0.f,0.f};
      const char* sb = (const char*)stage_s + lane * 16;
#pragma unroll
      for (int kk = 0; kk < 32; ++kk) {
        const half8 A0 = *(const half8*)(sb + kk * 2048);
        const half8 A1 = *(const half8*)(sb + kk * 2048 + 1024);
        a00 = __builtin_amdgcn_mfma_f32_16x16x32_f16(A0, wf0[kk], a00, 0, 0, 0);
        a01 = __builtin_amdgcn_mfma_f32_16x16x32_f16(A0, wf1[kk], a01, 0, 0, 0);
        a10 = __builtin_amdgcn_mfma_f32_16x16x32_f16(A1, wf0[kk], a10, 0, 0, 0);
        a11 = __builtin_amdgcn_mfma_f32_16x16x32_f16(A1, wf1[kk], a11, 0, 0, 0);
      }

      // gate exchange: rows = batch (M), cols = gate w * 32 + local dim (N)
      {
        const int colb = w * 32 + (lane & 15);
        const int rowb = (lane >> 4) * 4;
#pragma unroll
        for (int r2 = 0; r2 < 4; ++r2) {
          gates_s[(rowb + r2) * 132 + colb]           = a00[r2];
          gates_s[(rowb + r2) * 132 + colb + 16]      = a01[r2];
          gates_s[(16 + rowb + r2) * 132 + colb]      = a10[r2];
          gates_s[(16 + rowb + r2) * 132 + colb + 16] = a11[r2];
        }
      }
      __syncthreads();

      // activation
      float4 G[4];
#pragma unroll
      for (int g = 0; g < 4; ++g)
        G[g] = *(const float4*)&gates_s[b * 132 + g * 32 + d0];
#pragma unroll
      for (int dd = 0; dd < 4; ++dd) {
        const float gi = ((const float*)&G[0])[dd] + (float)((const _Float16*)&gxu[0])[dd] + bs[0][dd];
        const float gf = ((const float*)&G[1])[dd] + (float)((const _Float16*)&gxu[1])[dd] + bs[1][dd];
        const float gg = ((const float*)&G[2])[dd] + (float)((const _Float16*)&gxu[2])[dd] + bs[2][dd];
        const float go = ((const float*)&G[3])[dd] + (float)((const _Float16*)&gxu[3])[dd] + bs[3][dd];
        const float iv = sigmf(gi), fv = sigmf(gf);
        const float gv = tanhf_(gg), ov = sigmf(go);
        cc[dd] = fv * cc[dd] + iv * gv;
        hf[dd] = ov * tanhf_(cc[dd]);
        pk.h[dd] = (_Float16)hf[dd];
      }
      hv_keep = pk.u;
      *(ull*)&yloc[(size_t)(t + 1) * BH + b * H_ + j0] = hv_keep;   // plain/local
      if (isL1)
        *(float4*)&y1out[(size_t)t * BH + b * H_ + j0] =
            make_float4(hf[0], hf[1], hf[2], hf[3]);

      __syncthreads();                      // drain stores (incl. sc1 publish)
      if (tid == 0) announce(slotF, slotS, rank, (unsigned)(t + 2));
    }

    // L0 epilogue: publish final slot, announce, rank0 aggregates l0prog=T
    if (!isL1) {
      st_ag64(&g_y0pub[((size_t)T_ * BH + b * H_ + j0) >> 2], hv_keep);
      __syncthreads();
      if (tid == 0) announce(g_f0, g_s0, rank, (unsigned)(T_ + 2));
      if (rank == 0u) {
        slot_wait2(g_f0, g_s0, (unsigned)(T_ + 2), nullptr, 0u);
        if (tid == 0) st_ag(g_l0prog, (unsigned)T_);
      }
    }

    *(float4*)&outh[(isL1 ? BH : 0) + b * H_ + j0] = make_float4(hf[0], hf[1], hf[2], hf[3]);
    *(float4*)&outc[(isL1 ? BH : 0) + b * H_ + j0] = make_float4(cc[0], cc[1], cc[2], cc[3]);
    return;
  }

  // ============================ helper role ==============================
  __shared__ unsigned sh_hid;
  if (tid == 0) sh_hid = add_ag(g_heltick);
  __syncthreads();
  const unsigned hid = sh_hid;
  if (hid >= 128u) return;

  half8 wih0[32], wih1[32];
  {
    const int rw0 = (int)hid * 32 + (lane & 15);
    const int rw1 = rw0 + 16;
#pragma unroll
    for (int kk = 0; kk < 32; ++kk) {
      wih0[kk] = load8_cvt(Wih1 + (size_t)rw0 * H_ + kk * 32 + kgrp);
      wih1[kk] = load8_cvt(Wih1 + (size_t)rw1 * H_ + kk * 32 + kgrp);
    }
  }
  const int cg0 = (int)hid * 32 + (lane & 15);
  const int cg1 = cg0 + 16;
  short* ggx_s = (short*)g_ggx;

  for (int c = 0; c < NCH; ++c) {
    if (tid == 0) {
      int guard = 0;
      while (ld_ag(g_l0prog) < (unsigned)(c * TC + TC)) {
        __builtin_amdgcn_s_sleep(4);
        if (++guard > GUARD) break;
      }
    }
    __syncthreads();
    const int t0 = c * TC;

#pragma unroll 1
    for (int mt = 0; mt < 4; ++mt) {
      const int arow = w * 64 + mt * 16 + (lane & 15);        // 0..255
      const size_t abase = (((size_t)(t0 + (arow >> 5) + 1) * BH) +
                            (size_t)(arow & 31) * H_ + kgrp) >> 2;   // ull units
      f32x4 e0 = {0.f,0.f,0.f,0.f}, e1 = {0.f,0.f,0.f,0.f};
#pragma unroll
      for (int kk = 0; kk < 32; ++kk) {
        union { ull u[2]; half8 v; } a;
        a.u[0] = ld_ag64(&g_y0pub[abase + kk * 8]);
        a.u[1] = ld_ag64(&g_y0pub[abase + kk * 8 + 1]);
        e0 = __builtin_amdgcn_mfma_f32_16x16x32_f16(a.v, wih0[kk], e0, 0, 0, 0);
        e1 = __builtin_amdgcn_mfma_f32_16x16x32_f16(a.v, wih1[kk], e1, 0, 0, 0);
      }
      const int mrow = w * 64 + mt * 16 + (lane >> 4) * 4;
#pragma unroll
      for (int r = 0; r < 4; ++r) {
        const int m = mrow + r;
        const int tt = t0 + (m >> 5);
        const int bb = m & 31;
        const _Float16 v0 = (_Float16)e0[r];    // raw GEMM; bias added by L1
        const _Float16 v1 = (_Float16)e1[r];
        __hip_atomic_store(&ggx_s[((size_t)tt * B_ + bb) * GX + cg0],
                           __builtin_bit_cast(short, v0),
                           __ATOMIC_RELAXED, __HIP_MEMORY_SCOPE_AGENT);
        __hip_atomic_store(&ggx_s[((size_t)tt * B_ + bb) * GX + cg1],
                           __builtin_bit_cast(short, v1),
                           __ATOMIC_RELAXED, __HIP_MEMORY_SCOPE_AGENT);
      }
    }
    __syncthreads();                       // drain sc1 stores
    if (tid == 0) add_ag(&g_chunk[c * 32]);
  }
}

// ---------------------------------------------------------------------------
extern "C" void kernel_launch(void* const* d_in, const int* in_sizes, int n_in,
                              void* d_out, int out_size, void* d_ws, size_t ws_size,
                              hipStream_t stream) {
  (void)in_sizes; (void)n_in; (void)d_ws; (void)ws_size; (void)out_size;

  const int*   x    = (const int*)  d_in[0];
  const float* Hst  = (const float*)d_in[1];
  const float* Cst  = (const float*)d_in[2];
  const float* Wih0 = (const float*)d_in[3];
  const float* Whh0 = (const float*)d_in[4];
  const float* bih0 = (const float*)d_in[5];
  const float* bhh0 = (const float*)d_in[6];
  const float* Wih1 = (const float*)d_in[7];
  const float* Whh1 = (const float*)d_in[8];
  const float* bih1 = (const float*)d_in[9];
  const float* bhh1 = (const float*)d_in[10];

  float* out   = (float*)d_out;
  float* y1out = out;
  float* outh  = out + (size_t)T_ * BH;
  float* outc  = outh + (size_t)2 * BH;

  hipLaunchKernelGGL(init_bar_k, dim3(1), dim3(1024), 0, stream);
  hipLaunchKernelGGL(transpose_wih0, dim3(8192), dim3(256), 0, stream, Wih0);
  hipLaunchKernelGGL(lstm_fused, dim3(256), dim3(TPB), 0, stream,
                     Whh0, bih0, bhh0, Wih1, Whh1, bih1, bhh1,
                     x, Hst, Cst, y1out, outh, outc);
}

// Round 12
// 1798.006 us; speedup vs baseline: 33.2475x; 33.2475x over previous
//
#include <hip/hip_runtime.h>

#define DI __device__ __forceinline__

using half8 = __attribute__((ext_vector_type(8))) _Float16;
using f32x4 = __attribute__((ext_vector_type(4))) float;
using ull = unsigned long long;

static constexpr int T_ = 256;
static constexpr int B_ = 32;
static constexpr int H_ = 1024;
static constexpr int V_ = 8192;
static constexpr int TPB = 256;
static constexpr int BH = B_ * H_;        // 32768 elems
static constexpr int GX = 4 * H_;         // 4096 gate rows
static constexpr int TC = 8;              // helper chunk (steps)
static constexpr int NCH = T_ / TC;       // 32 chunks
static constexpr int GUARD = 2000000;     // sc1 poll cap (bounded, ~effectively never)

// ---- device state (re-initialized every launch by init kernel) ----
__device__ _Float16 g_y0loc[(T_ + 1) * BH];         // L0 h chain (XCD0 L2 traffic)
__device__ _Float16 g_y1loc[(T_ + 1) * BH];         // L1 h chain (XCD1 L2 traffic)
__device__ ull g_y0pub[(size_t)(T_ + 1) * BH / 4];  // L0 h published (sc1)
__device__ ull g_ggx[(size_t)T_ * B_ * GX / 4];     // helpers: y0@Wih1^T (no bias)
__device__ _Float16 g_Wt[(size_t)V_ * GX];          // W_ih0^T fp16: [vocab][4H]
__device__ unsigned g_xcdcnt[8 * 32];               // per-XCD election tickets
__device__ unsigned g_heltick[32];                  // global helper ticket
__device__ unsigned g_slot0[32 * 8];                // per-block round slots (sc1)
__device__ unsigned g_slot1[32 * 8];
__device__ unsigned g_l0prog[32];                   // y0pub slots 0..P valid (sc1)
__device__ unsigned g_chunk[NCH * 32];              // helper chunk arrivals (sc1)

__global__ void init_bar_k() {
  const int i = threadIdx.x;   // 1024 threads
  if (i < 256) { g_xcdcnt[i] = 0u; g_slot0[i] = 0u; g_slot1[i] = 0u; }
  if (i < 32)  { g_l0prog[i] = 0u; g_heltick[i] = 0u; }
  g_chunk[i] = 0u;             // NCH*32 = 1024
}

// ---------------------------------------------------------------------------
// Prepass: W_ih0 (4096 x 8192) f32 -> g_Wt (8192 x 4096) fp16
// ---------------------------------------------------------------------------
__global__ __launch_bounds__(256) void transpose_wih0(const float* __restrict__ in) {
  __shared__ _Float16 t[64][72];
  const int bc = blockIdx.x & 127;
  const int br = blockIdx.x >> 7;
  const int r0 = br * 64, v0 = bc * 64;
  const int tx = threadIdx.x & 15, ty = threadIdx.x >> 4;
#pragma unroll
  for (int it = 0; it < 4; ++it) {
    const int row = ty + it * 16;
    const float4 f = *(const float4*)&in[(size_t)(r0 + row) * V_ + v0 + tx * 4];
    t[tx * 4 + 0][row] = (_Float16)f.x;
    t[tx * 4 + 1][row] = (_Float16)f.y;
    t[tx * 4 + 2][row] = (_Float16)f.z;
    t[tx * 4 + 3][row] = (_Float16)f.w;
  }
  __syncthreads();
#pragma unroll
  for (int it = 0; it < 4; ++it) {
    const int vrow = ty + it * 16;
    union { _Float16 h[4]; ull u; } o;
    o.h[0] = t[vrow][tx * 4 + 0]; o.h[1] = t[vrow][tx * 4 + 1];
    o.h[2] = t[vrow][tx * 4 + 2]; o.h[3] = t[vrow][tx * 4 + 3];
    *(ull*)&g_Wt[(size_t)(v0 + vrow) * GX + r0 + tx * 4] = o.u;
  }
}

// ---------------------------------------------------------------------------
DI unsigned ld_ag(const unsigned* p) { return __hip_atomic_load(p, __ATOMIC_RELAXED, __HIP_MEMORY_SCOPE_AGENT); }
DI void st_ag(unsigned* p, unsigned v) { __hip_atomic_store(p, v, __ATOMIC_RELAXED, __HIP_MEMORY_SCOPE_AGENT); }
DI unsigned add_ag(unsigned* p) { return __hip_atomic_fetch_add(p, 1u, __ATOMIC_RELAXED, __HIP_MEMORY_SCOPE_AGENT); }
DI void st_ag64(ull* p, ull v) { __hip_atomic_store(p, v, __ATOMIC_RELAXED, __HIP_MEMORY_SCOPE_AGENT); }
DI ull ld_ag64(const ull* p) { return __hip_atomic_load(p, __ATOMIC_RELAXED, __HIP_MEMORY_SCOPE_AGENT); }

DI float sigmf(float v) { return 1.0f / (1.0f + __expf(-v)); }
DI float tanhf_(float v) { return 1.0f - 2.0f / (__expf(2.0f * v) + 1.0f); }

DI half8 load8_cvt(const float* __restrict__ p) {
  const float4* q = (const float4*)p;
  float4 a = q[0], b = q[1];
  half8 r;
  r[0] = (_Float16)a.x; r[1] = (_Float16)a.y; r[2] = (_Float16)a.z; r[3] = (_Float16)a.w;
  r[4] = (_Float16)b.x; r[5] = (_Float16)b.y; r[6] = (_Float16)b.z; r[7] = (_Float16)b.w;
  return r;
}

// In-wave all-peer wait: lane i polls slot i (one vector sc1 load per iter);
// lane 32 optionally polls an extra gate. Reconverges when all satisfied.
// (Proven R9/R10; sc0 variant falsified in R11.)
DI void slot_wait(unsigned* slots, unsigned r, const unsigned* extra,
                  unsigned extraTgt) {
  const int tid = threadIdx.x;
  if (tid < 64) {
    if (tid < 32) {
      int guard = 0;
      while (ld_ag(&slots[tid * 8]) < r) {
        __builtin_amdgcn_s_sleep(1);
        if (++guard > GUARD) break;
      }
    } else if (tid == 32 && extra) {
      int guard = 0;
      while (ld_ag(extra) < extraTgt) {
        __builtin_amdgcn_s_sleep(1);
        if (++guard > GUARD) break;
      }
    }
  }
  __syncthreads();
}

// Stage one 32x1024 fp16 matrix (64KB) global->LDS in MFMA-fragment order
// (R11-proven conflict-free): dest chunk c = kk*128 + half*64 + l holds
// h[half*16 + (l&15)][kk*32 + (l>>4)*8 .. +8]; wave reads are base + lane*16.
DI void stage_h(_Float16* ldsbase, const _Float16* src, int w) {
  const int lane = (int)(threadIdx.x & 63);
#pragma unroll
  for (int i = 0; i < 16; ++i) {
    const int c = (w * 16 + i) * 64 + lane;          // dest 16B chunk id
    const int kk = c >> 7;
    const int half = (c >> 6) & 1;
    const int l = c & 63;
    const int row = half * 16 + (l & 15);
    const int srcchunk = row * 128 + kk * 4 + (l >> 4);
    __builtin_amdgcn_global_load_lds(
        (const __attribute__((address_space(1))) void*)((const char*)src + (size_t)srcchunk * 16),
        (__attribute__((address_space(3))) void*)((char*)ldsbase + (size_t)(w * 16 + i) * 1024),
        16, 0, 0);
  }
}

// ---------------------------------------------------------------------------
__global__ __launch_bounds__(TPB, 1) void lstm_fused(
    const float* __restrict__ Whh0,
    const float* __restrict__ bih0, const float* __restrict__ bhh0,
    const float* __restrict__ Wih1,
    const float* __restrict__ Whh1,
    const float* __restrict__ bih1, const float* __restrict__ bhh1,
    const int* __restrict__ x,
    const float* __restrict__ Hst,
    const float* __restrict__ Cst,
    float* __restrict__ y1out,
    float* __restrict__ outh,
    float* __restrict__ outc)
{
  const int tid = threadIdx.x;
  const int lane = tid & 63;
  const int w = tid >> 6;

  __shared__ _Float16 stage_s[BH];       // 64 KB
  __shared__ float gates_s[32 * 132];    // 16.5 KB -> ~81KB total -> 1 block/CU
  __shared__ unsigned sh_xcc, sh_rank;

  if (tid == 0) {
    unsigned xc;
    asm volatile("s_getreg_b32 %0, hwreg(HW_REG_XCC_ID)" : "=s"(xc));
    xc &= 7u;
    sh_xcc = xc;
    sh_rank = __hip_atomic_fetch_add(&g_xcdcnt[xc * 32], 1u,
                                     __ATOMIC_RELAXED, __HIP_MEMORY_SCOPE_AGENT);
  }
  __syncthreads();
  const unsigned xcc = sh_xcc;
  const unsigned rank = sh_rank;

  const int kgrp = (lane >> 4) * 8;      // halfs

  // =========================== recurrence role ===========================
  if (xcc <= 1u && rank < 32u) {
    const bool isL1 = (xcc == 1u);
    const int jbase = (int)rank * 32;    // this block's 32 hidden dims
    const float* Whh = isL1 ? Whh1 : Whh0;
    const float* bih = isL1 ? bih1 : bih0;
    const float* bhh = isL1 ? bhh1 : bhh0;
    _Float16* yloc = isL1 ? g_y1loc : g_y0loc;
    unsigned* slots = isL1 ? g_slot1 : g_slot0;

    // W_hh fragments -> VGPRs (wave w == gate w; two 16-dim N-tiles)
    half8 wf0[32], wf1[32];
    {
      const int rw0 = w * H_ + jbase + (lane & 15);
      const int rw1 = rw0 + 16;
#pragma unroll
      for (int kk = 0; kk < 32; ++kk) {
        wf0[kk] = load8_cvt(Whh + (size_t)rw0 * H_ + kk * 32 + kgrp);
        wf1[kk] = load8_cvt(Whh + (size_t)rw1 * H_ + kk * 32 + kgrp);
      }
    }

    const int b = tid >> 3;
    const int d0 = (tid & 7) * 4;
    const int j0 = jbase + d0;

    float bs[4][4];
#pragma unroll
    for (int g = 0; g < 4; ++g)
#pragma unroll
      for (int dd = 0; dd < 4; ++dd)
        bs[g][dd] = bih[g * H_ + j0 + dd] + bhh[g * H_ + j0 + dd];

    float cc[4], hf[4];
    {
      const float4 hi = *(const float4*)&Hst[(isL1 ? BH : 0) + b * H_ + j0];
      const float4 ci = *(const float4*)&Cst[(isL1 ? BH : 0) + b * H_ + j0];
      cc[0] = ci.x; cc[1] = ci.y; cc[2] = ci.z; cc[3] = ci.w;
      hf[0] = hi.x; hf[1] = hi.y; hf[2] = hi.z; hf[3] = hi.w;
    }
    union { _Float16 h[4]; ull u; } pk;
#pragma unroll
    for (int dd = 0; dd < 4; ++dd) pk.h[dd] = (_Float16)hf[dd];
    ull hv_keep = pk.u;
    *(ull*)&yloc[(size_t)b * H_ + j0] = hv_keep;     // slot 0 (plain, local L2)

    __syncthreads();                                  // drain slot-0 stores
    if (tid == 0) st_ag(&slots[rank * 8], 1u);        // announce round 1

    for (int t = 0; t < T_; ++t) {
      // input-side gates: prefetch BEFORE the wait when legal
      ull gxu[4];
      if (!isL1) {
        const int xv = x[t * B_ + b];
        const _Float16* gp = g_Wt + (size_t)xv * GX + j0;
#pragma unroll
        for (int g = 0; g < 4; ++g) gxu[g] = *(const ull*)(gp + g * H_);
      } else if (t & (TC - 1)) {
        const size_t gbase = (((size_t)t * B_ + b) * GX + j0) >> 2;
#pragma unroll
        for (int g = 0; g < 4; ++g) gxu[g] = ld_ag64(&g_ggx[gbase + (size_t)(g * H_ >> 2)]);
      }

      // ---- wait: all 32 peers at round t+1 (+ chunk gate for L1) ----
      const unsigned r = (unsigned)(t + 1);
      if (isL1 && (t & (TC - 1)) == 0)
        slot_wait(slots, r, &g_chunk[(t / TC) * 32], 128u);
      else
        slot_wait(slots, r, nullptr, 0u);

      if (!isL1) {
        if (rank == 0u && tid == 0 && t >= 1) st_ag(g_l0prog, (unsigned)(t - 1));
        st_ag64(&g_y0pub[((size_t)t * BH + b * H_ + j0) >> 2], hv_keep);
      } else if ((t & (TC - 1)) == 0) {
        const size_t gbase = (((size_t)t * B_ + b) * GX + j0) >> 2;
#pragma unroll
        for (int g = 0; g < 4; ++g) gxu[g] = ld_ag64(&g_ggx[gbase + (size_t)(g * H_ >> 2)]);
      }

      // stage h(t) 64KB -> LDS in fragment order (same-XCD L2 hits)
      stage_h(stage_s, yloc + (size_t)t * BH, w);
      __syncthreads();

      // MFMA: 2 M-tiles x 2 N-tiles x K=1024; conflict-free lane-linear reads
      f32x4 a00 = {0.f,0.f,0.f,0.f}, a01 = {0.f,0.f,0.f,0.f};
      f32x4 a10 = {0.f,0.f,0.f,0.f}, a11 = {0.f,0.f,0.f,0.f};
      const char* sb = (const char*)stage_s + lane * 16;
#pragma unroll
      for (int kk = 0; kk < 32; ++kk) {
        const half8 A0 = *(const half8*)(sb + kk * 2048);
        const half8 A1 = *(const half8*)(sb + kk * 2048 + 1024);
        a00 = __builtin_amdgcn_mfma_f32_16x16x32_f16(A0, wf0[kk], a00, 0, 0, 0);
        a01 = __builtin_amdgcn_mfma_f32_16x16x32_f16(A0, wf1[kk], a01, 0, 0, 0);
        a10 = __builtin_amdgcn_mfma_f32_16x16x32_f16(A1, wf0[kk], a10, 0, 0, 0);
        a11 = __builtin_amdgcn_mfma_f32_16x16x32_f16(A1, wf1[kk], a11, 0, 0, 0);
      }

      // gate exchange: rows = batch (M), cols = gate w * 32 + local dim (N)
      {
        const int colb = w * 32 + (lane & 15);
        const int rowb = (lane >> 4) * 4;
#pragma unroll
        for (int r2 = 0; r2 < 4; ++r2) {
          gates_s[(rowb + r2) * 132 + colb]           = a00[r2];
          gates_s[(rowb + r2) * 132 + colb + 16]      = a01[r2];
          gates_s[(16 + rowb + r2) * 132 + colb]      = a10[r2];
          gates_s[(16 + rowb + r2) * 132 + colb + 16] = a11[r2];
        }
      }
      __syncthreads();

      // activation (float4 gate reads)
      float4 G[4];
#pragma unroll
      for (int g = 0; g < 4; ++g)
        G[g] = *(const float4*)&gates_s[b * 132 + g * 32 + d0];
#pragma unroll
      for (int dd = 0; dd < 4; ++dd) {
        const float gi = ((const float*)&G[0])[dd] + (float)((const _Float16*)&gxu[0])[dd] + bs[0][dd];
        const float gf = ((const float*)&G[1])[dd] + (float)((const _Float16*)&gxu[1])[dd] + bs[1][dd];
        const float gg = ((const float*)&G[2])[dd] + (float)((const _Float16*)&gxu[2])[dd] + bs[2][dd];
        const float go = ((const float*)&G[3])[dd] + (float)((const _Float16*)&gxu[3])[dd] + bs[3][dd];
        const float iv = sigmf(gi), fv = sigmf(gf);
        const float gv = tanhf_(gg), ov = sigmf(go);
        cc[dd] = fv * cc[dd] + iv * gv;
        hf[dd] = ov * tanhf_(cc[dd]);
        pk.h[dd] = (_Float16)hf[dd];
      }
      hv_keep = pk.u;
      *(ull*)&yloc[(size_t)(t + 1) * BH + b * H_ + j0] = hv_keep;   // plain/local
      if (isL1)
        *(float4*)&y1out[(size_t)t * BH + b * H_ + j0] =
            make_float4(hf[0], hf[1], hf[2], hf[3]);

      __syncthreads();                      // drain stores (incl. sc1 publish)
      if (tid == 0) st_ag(&slots[rank * 8], (unsigned)(t + 2));
    }

    // L0 epilogue: publish final slot, announce, rank0 aggregates l0prog=T
    if (!isL1) {
      st_ag64(&g_y0pub[((size_t)T_ * BH + b * H_ + j0) >> 2], hv_keep);
      __syncthreads();
      if (tid == 0) st_ag(&g_slot0[rank * 8], (unsigned)(T_ + 2));
      if (rank == 0u) {
        slot_wait(g_slot0, (unsigned)(T_ + 2), nullptr, 0u);
        if (tid == 0) st_ag(g_l0prog, (unsigned)T_);
      }
    }

    *(float4*)&outh[(isL1 ? BH : 0) + b * H_ + j0] = make_float4(hf[0], hf[1], hf[2], hf[3]);
    *(float4*)&outc[(isL1 ? BH : 0) + b * H_ + j0] = make_float4(cc[0], cc[1], cc[2], cc[3]);
    return;
  }

  // ============================ helper role ==============================
  __shared__ unsigned sh_hid;
  if (tid == 0) sh_hid = add_ag(g_heltick);
  __syncthreads();
  const unsigned hid = sh_hid;
  if (hid >= 128u) return;

  half8 wih0[32], wih1[32];
  {
    const int rw0 = (int)hid * 32 + (lane & 15);
    const int rw1 = rw0 + 16;
#pragma unroll
    for (int kk = 0; kk < 32; ++kk) {
      wih0[kk] = load8_cvt(Wih1 + (size_t)rw0 * H_ + kk * 32 + kgrp);
      wih1[kk] = load8_cvt(Wih1 + (size_t)rw1 * H_ + kk * 32 + kgrp);
    }
  }
  const int cg0 = (int)hid * 32 + (lane & 15);
  const int cg1 = cg0 + 16;
  short* ggx_s = (short*)g_ggx;

  for (int c = 0; c < NCH; ++c) {
    if (tid == 0) {
      int guard = 0;
      while (ld_ag(g_l0prog) < (unsigned)(c * TC + TC)) {
        __builtin_amdgcn_s_sleep(4);
        if (++guard > GUARD) break;
      }
    }
    __syncthreads();
    const int t0 = c * TC;

#pragma unroll 1
    for (int mt = 0; mt < 4; ++mt) {
      const int arow = w * 64 + mt * 16 + (lane & 15);        // 0..255
      const size_t abase = (((size_t)(t0 + (arow >> 5) + 1) * BH) +
                            (size_t)(arow & 31) * H_ + kgrp) >> 2;   // ull units
      f32x4 e0 = {0.f,0.f,0.f,0.f}, e1 = {0.f,0.f,0.f,0.f};
#pragma unroll
      for (int kk = 0; kk < 32; ++kk) {
        union { ull u[2]; half8 v; } a;
        a.u[0] = ld_ag64(&g_y0pub[abase + kk * 8]);
        a.u[1] = ld_ag64(&g_y0pub[abase + kk * 8 + 1]);
        e0 = __builtin_amdgcn_mfma_f32_16x16x32_f16(a.v, wih0[kk], e0, 0, 0, 0);
        e1 = __builtin_amdgcn_mfma_f32_16x16x32_f16(a.v, wih1[kk], e1, 0, 0, 0);
      }
      const int mrow = w * 64 + mt * 16 + (lane >> 4) * 4;
#pragma unroll
      for (int r = 0; r < 4; ++r) {
        const int m = mrow + r;
        const int tt = t0 + (m >> 5);
        const int bb = m & 31;
        const _Float16 v0 = (_Float16)e0[r];    // raw GEMM; bias added by L1
        const _Float16 v1 = (_Float16)e1[r];
        __hip_atomic_store(&ggx_s[((size_t)tt * B_ + bb) * GX + cg0],
                           __builtin_bit_cast(short, v0),
                           __ATOMIC_RELAXED, __HIP_MEMORY_SCOPE_AGENT);
        __hip_atomic_store(&ggx_s[((size_t)tt * B_ + bb) * GX + cg1],
                           __builtin_bit_cast(short, v1),
                           __ATOMIC_RELAXED, __HIP_MEMORY_SCOPE_AGENT);
      }
    }
    __syncthreads();                       // drain sc1 stores
    if (tid == 0) add_ag(&g_chunk[c * 32]);
  }
}

// ---------------------------------------------------------------------------
extern "C" void kernel_launch(void* const* d_in, const int* in_sizes, int n_in,
                              void* d_out, int out_size, void* d_ws, size_t ws_size,
                              hipStream_t stream) {
  (void)in_sizes; (void)n_in; (void)d_ws; (void)ws_size; (void)out_size;

  const int*   x    = (const int*)  d_in[0];
  const float* Hst  = (const float*)d_in[1];
  const float* Cst  = (const float*)d_in[2];
  const float* Wih0 = (const float*)d_in[3];
  const float* Whh0 = (const float*)d_in[4];
  const float* bih0 = (const float*)d_in[5];
  const float* bhh0 = (const float*)d_in[6];
  const float* Wih1 = (const float*)d_in[7];
  const float* Whh1 = (const float*)d_in[8];
  const float* bih1 = (const float*)d_in[9];
  const float* bhh1 = (const float*)d_in[10];

  float* out   = (float*)d_out;
  float* y1out = out;
  float* outh  = out + (size_t)T_ * BH;
  float* outc  = outh + (size_t)2 * BH;

  hipLaunchKernelGGL(init_bar_k, dim3(1), dim3(1024), 0, stream);
  hipLaunchKernelGGL(transpose_wih0, dim3(8192), dim3(256), 0, stream, Wih0);
  hipLaunchKernelGGL(lstm_fused, dim3(256), dim3(TPB), 0, stream,
                     Whh0, bih0, bhh0, Wih1, Whh1, bih1, bhh1,
                     x, Hst, Cst, y1out, outh, outc);
}

// Round 14
// 1414.756 us; speedup vs baseline: 42.2541x; 1.2709x over previous
//
#include <hip/hip_runtime.h>

#define DI __device__ __forceinline__

using half8 = __attribute__((ext_vector_type(8))) _Float16;
using f32x4 = __attribute__((ext_vector_type(4))) float;
using ull = unsigned long long;

static constexpr int T_ = 256;
static constexpr int B_ = 32;
static constexpr int H_ = 1024;
static constexpr int V_ = 8192;
static constexpr int TPB = 256;
static constexpr int BH = B_ * H_;        // 32768 elems
static constexpr int GX = 4 * H_;         // 4096 gate rows
static constexpr int TC = 8;              // helper chunk (steps)
static constexpr int NCH = T_ / TC;       // 32 chunks
static constexpr int GUARD = 60000;       // poll cap: bounded failure, no timeout

// ---- device state (re-initialized every launch by init kernel) ----
__device__ _Float16 g_y0loc[(T_ + 1) * BH];         // L0 h chain (XCD0 L2 traffic)
__device__ _Float16 g_y1loc[(T_ + 1) * BH];         // L1 h chain (XCD1 L2 traffic)
__device__ ull g_y0pub[(size_t)(T_ + 1) * BH / 4];  // L0 h published (sc1)
__device__ ull g_ggx[(size_t)T_ * B_ * GX / 4];     // helpers: y0@Wih1^T (no bias)
__device__ _Float16 g_Wt[(size_t)V_ * GX];          // W_ih0^T fp16: [vocab][4H]
__device__ unsigned g_xcdcnt[8 * 32];               // per-XCD election tickets
__device__ unsigned g_heltick[32];                  // global helper ticket
__device__ unsigned g_slot0[32 * 8];                // per-block round slots (sc1)
__device__ unsigned g_slot1[32 * 8];
__device__ unsigned g_l0prog[32];                   // y0pub slots 0..P valid (sc1)
__device__ unsigned g_chunk[NCH * 32];              // helper chunk arrivals (sc1)

__global__ void init_bar_k() {
  const int i = threadIdx.x;   // 1024 threads
  if (i < 256) { g_xcdcnt[i] = 0u; g_slot0[i] = 0u; g_slot1[i] = 0u; }
  if (i < 32)  { g_l0prog[i] = 0u; g_heltick[i] = 0u; }
  g_chunk[i] = 0u;             // NCH*32 = 1024
}

// ---------------------------------------------------------------------------
// Prepass: W_ih0 (4096 x 8192) f32 -> g_Wt (8192 x 4096) fp16
// ---------------------------------------------------------------------------
__global__ __launch_bounds__(256) void transpose_wih0(const float* __restrict__ in) {
  __shared__ _Float16 t[64][72];
  const int bc = blockIdx.x & 127;
  const int br = blockIdx.x >> 7;
  const int r0 = br * 64, v0 = bc * 64;
  const int tx = threadIdx.x & 15, ty = threadIdx.x >> 4;
#pragma unroll
  for (int it = 0; it < 4; ++it) {
    const int row = ty + it * 16;
    const float4 f = *(const float4*)&in[(size_t)(r0 + row) * V_ + v0 + tx * 4];
    t[tx * 4 + 0][row] = (_Float16)f.x;
    t[tx * 4 + 1][row] = (_Float16)f.y;
    t[tx * 4 + 2][row] = (_Float16)f.z;
    t[tx * 4 + 3][row] = (_Float16)f.w;
  }
  __syncthreads();
#pragma unroll
  for (int it = 0; it < 4; ++it) {
    const int vrow = ty + it * 16;
    union { _Float16 h[4]; ull u; } o;
    o.h[0] = t[vrow][tx * 4 + 0]; o.h[1] = t[vrow][tx * 4 + 1];
    o.h[2] = t[vrow][tx * 4 + 2]; o.h[3] = t[vrow][tx * 4 + 3];
    *(ull*)&g_Wt[(size_t)(v0 + vrow) * GX + r0 + tx * 4] = o.u;
  }
}

// ---------------------------------------------------------------------------
DI unsigned ld_ag(const unsigned* p) { return __hip_atomic_load(p, __ATOMIC_RELAXED, __HIP_MEMORY_SCOPE_AGENT); }
DI void st_ag(unsigned* p, unsigned v) { __hip_atomic_store(p, v, __ATOMIC_RELAXED, __HIP_MEMORY_SCOPE_AGENT); }
DI unsigned add_ag(unsigned* p) { return __hip_atomic_fetch_add(p, 1u, __ATOMIC_RELAXED, __HIP_MEMORY_SCOPE_AGENT); }
DI void st_ag64(ull* p, ull v) { __hip_atomic_store(p, v, __ATOMIC_RELAXED, __HIP_MEMORY_SCOPE_AGENT); }
DI ull ld_ag64(const ull* p) { return __hip_atomic_load(p, __ATOMIC_RELAXED, __HIP_MEMORY_SCOPE_AGENT); }

DI float sigmf(float v) { return 1.0f / (1.0f + __expf(-v)); }
DI float tanhf_(float v) { return 1.0f - 2.0f / (__expf(2.0f * v) + 1.0f); }

DI half8 load8_cvt(const float* __restrict__ p) {
  const float4* q = (const float4*)p;
  float4 a = q[0], b = q[1];
  half8 r;
  r[0] = (_Float16)a.x; r[1] = (_Float16)a.y; r[2] = (_Float16)a.z; r[3] = (_Float16)a.w;
  r[4] = (_Float16)b.x; r[5] = (_Float16)b.y; r[6] = (_Float16)b.z; r[7] = (_Float16)b.w;
  return r;
}

// In-wave all-peer wait: lane i polls slot i (one vector sc1 load per iter);
// lane 32 optionally polls an extra gate. Reconverges when all satisfied.
DI void slot_wait(unsigned* slots, unsigned r, const unsigned* extra,
                  unsigned extraTgt) {
  const int tid = threadIdx.x;
  if (tid < 64) {
    if (tid < 32) {
      int guard = 0;
      while (ld_ag(&slots[tid * 8]) < r) {
        __builtin_amdgcn_s_sleep(1);
        if (++guard > GUARD) break;
      }
    } else if (tid == 32 && extra) {
      int guard = 0;
      while (ld_ag(extra) < extraTgt) {
        __builtin_amdgcn_s_sleep(1);
        if (++guard > GUARD) break;
      }
    }
  }
  __syncthreads();
}

// stage one 32x1024 fp16 matrix (64KB) global->LDS via global_load_lds,
// swizzle applied by permuting the SOURCE chunks (dest stays linear, m201).
DI void stage_h(_Float16* ldsbase, const _Float16* src, int w) {
  const int lane = (int)(threadIdx.x & 63);
#pragma unroll
  for (int i = 0; i < 16; ++i) {
    const int d = (w * 16 + i) * 64 + lane;          // dest 16B chunk id
    const int row = d >> 7;
    const int cir = d & 127;
    const int sc = row * 128 + (cir ^ (row & 7));    // source chunk
    __builtin_amdgcn_global_load_lds(
        (const __attribute__((address_space(1))) void*)((const char*)src + (size_t)sc * 16),
        (__attribute__((address_space(3))) void*)((char*)ldsbase + (size_t)(w * 16 + i) * 1024),
        16, 0, 0);
  }
}

// swizzled A-fragment read from staged LDS
DI half8 lds_a(const _Float16* stg, int arow, int kk, int kgb) {
  unsigned off = (unsigned)(arow * 2048 + kk * 64 + kgb);
  off ^= (unsigned)((arow & 7) << 4);
  return *(const half8*)((const char*)stg + off);
}

// ---------------------------------------------------------------------------
__global__ __launch_bounds__(TPB, 1) void lstm_fused(
    const float* __restrict__ Whh0,
    const float* __restrict__ bih0, const float* __restrict__ bhh0,
    const float* __restrict__ Wih1,
    const float* __restrict__ Whh1,
    const float* __restrict__ bih1, const float* __restrict__ bhh1,
    const int* __restrict__ x,
    const float* __restrict__ Hst,
    const float* __restrict__ Cst,
    float* __restrict__ y1out,
    float* __restrict__ outh,
    float* __restrict__ outc)
{
  const int tid = threadIdx.x;
  const int lane = tid & 63;
  const int w = tid >> 6;

  __shared__ _Float16 stage_s[BH];       // 64 KB
  __shared__ float gates_s[32 * 132];    // 16.5 KB -> ~81KB total -> 1 block/CU
  __shared__ unsigned sh_xcc, sh_rank;

  if (tid == 0) {
    unsigned xc;
    asm volatile("s_getreg_b32 %0, hwreg(HW_REG_XCC_ID)" : "=s"(xc));
    xc &= 7u;
    sh_xcc = xc;
    sh_rank = __hip_atomic_fetch_add(&g_xcdcnt[xc * 32], 1u,
                                     __ATOMIC_RELAXED, __HIP_MEMORY_SCOPE_AGENT);
  }
  __syncthreads();
  const unsigned xcc = sh_xcc;
  const unsigned rank = sh_rank;

  const int kgrp = (lane >> 4) * 8;      // halfs
  const int kgb = (lane >> 4) * 16;      // bytes

  // =========================== recurrence role ===========================
  if (xcc <= 1u && rank < 32u) {
    const bool isL1 = (xcc == 1u);
    const int jbase = (int)rank * 32;    // this block's 32 hidden dims
    const float* Whh = isL1 ? Whh1 : Whh0;
    const float* bih = isL1 ? bih1 : bih0;
    const float* bhh = isL1 ? bhh1 : bhh0;
    _Float16* yloc = isL1 ? g_y1loc : g_y0loc;
    unsigned* slots = isL1 ? g_slot1 : g_slot0;

    // W_hh fragments -> VGPRs (wave w == gate w; two 16-dim N-tiles)
    half8 wf0[32], wf1[32];
    {
      const int rw0 = w * H_ + jbase + (lane & 15);
      const int rw1 = rw0 + 16;
#pragma unroll
      for (int kk = 0; kk < 32; ++kk) {
        wf0[kk] = load8_cvt(Whh + (size_t)rw0 * H_ + kk * 32 + kgrp);
        wf1[kk] = load8_cvt(Whh + (size_t)rw1 * H_ + kk * 32 + kgrp);
      }
    }

    const int b = tid >> 3;
    const int d0 = (tid & 7) * 4;
    const int j0 = jbase + d0;

    float bs[4][4];
#pragma unroll
    for (int g = 0; g < 4; ++g)
#pragma unroll
      for (int dd = 0; dd < 4; ++dd)
        bs[g][dd] = bih[g * H_ + j0 + dd] + bhh[g * H_ + j0 + dd];

    float cc[4], hf[4];
    {
      const float4 hi = *(const float4*)&Hst[(isL1 ? BH : 0) + b * H_ + j0];
      const float4 ci = *(const float4*)&Cst[(isL1 ? BH : 0) + b * H_ + j0];
      cc[0] = ci.x; cc[1] = ci.y; cc[2] = ci.z; cc[3] = ci.w;
      hf[0] = hi.x; hf[1] = hi.y; hf[2] = hi.z; hf[3] = hi.w;
    }
    union { _Float16 h[4]; ull u; } pk;
#pragma unroll
    for (int dd = 0; dd < 4; ++dd) pk.h[dd] = (_Float16)hf[dd];
    ull hv_keep = pk.u;
    *(ull*)&yloc[(size_t)b * H_ + j0] = hv_keep;     // slot 0 (plain, local L2)

    __syncthreads();                                  // drain slot-0 stores
    if (tid == 0) st_ag(&slots[rank * 8], 1u);        // announce round 1

    for (int t = 0; t < T_; ++t) {
      // input-side gates: prefetch BEFORE the wait when legal
      ull gxu[4];
      if (!isL1) {
        const int xv = x[t * B_ + b];
        const _Float16* gp = g_Wt + (size_t)xv * GX + j0;
#pragma unroll
        for (int g = 0; g < 4; ++g) gxu[g] = *(const ull*)(gp + g * H_);
      } else if (t & (TC - 1)) {
        const size_t gbase = (((size_t)t * B_ + b) * GX + j0) >> 2;
#pragma unroll
        for (int g = 0; g < 4; ++g) gxu[g] = ld_ag64(&g_ggx[gbase + (size_t)(g * H_ >> 2)]);
      }

      // ---- wait: all 32 peers at round t+1 (+ chunk gate for L1) ----
      const unsigned r = (unsigned)(t + 1);
      if (isL1 && (t & (TC - 1)) == 0)
        slot_wait(slots, r, &g_chunk[(t / TC) * 32], 128u);
      else
        slot_wait(slots, r, nullptr, 0u);

      if (!isL1) {
        if (rank == 0u && tid == 0 && t >= 1) st_ag(g_l0prog, (unsigned)(t - 1));
        st_ag64(&g_y0pub[((size_t)t * BH + b * H_ + j0) >> 2], hv_keep);
      } else if ((t & (TC - 1)) == 0) {
        const size_t gbase = (((size_t)t * B_ + b) * GX + j0) >> 2;
#pragma unroll
        for (int g = 0; g < 4; ++g) gxu[g] = ld_ag64(&g_ggx[gbase + (size_t)(g * H_ >> 2)]);
      }

      // stage h(t) 64KB -> LDS (same-XCD L2 hits)
      stage_h(stage_s, yloc + (size_t)t * BH, w);
      __syncthreads();

      // MFMA: 2 M-tiles x 2 N-tiles x K=1024
      f32x4 a00 = {0.f,0.f,0.f,0.f}, a01 = {0.f,0.f,0.f,0.f};
      f32x4 a10 = {0.f,0.f,0.f,0.f}, a11 = {0.f,0.f,0.f,0.f};
#pragma unroll
      for (int kk = 0; kk < 32; ++kk) {
        const half8 A0 = lds_a(stage_s, (lane & 15), kk, kgb);
        const half8 A1 = lds_a(stage_s, 16 + (lane & 15), kk, kgb);
        a00 = __builtin_amdgcn_mfma_f32_16x16x32_f16(A0, wf0[kk], a00, 0, 0, 0);
        a01 = __builtin_amdgcn_mfma_f32_16x16x32_f16(A0, wf1[kk], a01, 0, 0, 0);
        a10 = __builtin_amdgcn_mfma_f32_16x16x32_f16(A1, wf0[kk], a10, 0, 0, 0);
        a11 = __builtin_amdgcn_mfma_f32_16x16x32_f16(A1, wf1[kk], a11, 0, 0, 0);
      }

      // gate exchange: rows = batch (M), cols = gate w * 32 + local dim (N)
      {
        const int colb = w * 32 + (lane & 15);
        const int rowb = (lane >> 4) * 4;
#pragma unroll
        for (int r2 = 0; r2 < 4; ++r2) {
          gates_s[(rowb + r2) * 132 + colb]           = a00[r2];
          gates_s[(rowb + r2) * 132 + colb + 16]      = a01[r2];
          gates_s[(16 + rowb + r2) * 132 + colb]      = a10[r2];
          gates_s[(16 + rowb + r2) * 132 + colb + 16] = a11[r2];
        }
      }
      __syncthreads();

      // activation (float4 gate reads)
      float4 G[4];
#pragma unroll
      for (int g = 0; g < 4; ++g)
        G[g] = *(const float4*)&gates_s[b * 132 + g * 32 + d0];
#pragma unroll
      for (int dd = 0; dd < 4; ++dd) {
        const float gi = ((const float*)&G[0])[dd] + (float)((const _Float16*)&gxu[0])[dd] + bs[0][dd];
        const float gf = ((const float*)&G[1])[dd] + (float)((const _Float16*)&gxu[1])[dd] + bs[1][dd];
        const float gg = ((const float*)&G[2])[dd] + (float)((const _Float16*)&gxu[2])[dd] + bs[2][dd];
        const float go = ((const float*)&G[3])[dd] + (float)((const _Float16*)&gxu[3])[dd] + bs[3][dd];
        const float iv = sigmf(gi), fv = sigmf(gf);
        const float gv = tanhf_(gg), ov = sigmf(go);
        cc[dd] = fv * cc[dd] + iv * gv;
        hf[dd] = ov * tanhf_(cc[dd]);
        pk.h[dd] = (_Float16)hf[dd];
      }
      hv_keep = pk.u;
      *(ull*)&yloc[(size_t)(t + 1) * BH + b * H_ + j0] = hv_keep;   // plain/local
      if (isL1)
        *(float4*)&y1out[(size_t)t * BH + b * H_ + j0] =
            make_float4(hf[0], hf[1], hf[2], hf[3]);

      __syncthreads();                      // drain stores (incl. sc1 publish)
      if (tid == 0) st_ag(&slots[rank * 8], (unsigned)(t + 2));
    }

    // L0 epilogue: publish final slot, announce, rank0 aggregates l0prog=T
    if (!isL1) {
      st_ag64(&g_y0pub[((size_t)T_ * BH + b * H_ + j0) >> 2], hv_keep);
      __syncthreads();
      if (tid == 0) st_ag(&g_slot0[rank * 8], (unsigned)(T_ + 2));
      if (rank == 0u) {
        slot_wait(g_slot0, (unsigned)(T_ + 2), nullptr, 0u);
        if (tid == 0) st_ag(g_l0prog, (unsigned)T_);
      }
    }

    *(float4*)&outh[(isL1 ? BH : 0) + b * H_ + j0] = make_float4(hf[0], hf[1], hf[2], hf[3]);
    *(float4*)&outc[(isL1 ? BH : 0) + b * H_ + j0] = make_float4(cc[0], cc[1], cc[2], cc[3]);
    return;
  }

  // ============================ helper role ==============================
  __shared__ unsigned sh_hid;
  if (tid == 0) sh_hid = add_ag(g_heltick);
  __syncthreads();
  const unsigned hid = sh_hid;
  if (hid >= 128u) return;

  half8 wih0[32], wih1[32];
  {
    const int rw0 = (int)hid * 32 + (lane & 15);
    const int rw1 = rw0 + 16;
#pragma unroll
    for (int kk = 0; kk < 32; ++kk) {
      wih0[kk] = load8_cvt(Wih1 + (size_t)rw0 * H_ + kk * 32 + kgrp);
      wih1[kk] = load8_cvt(Wih1 + (size_t)rw1 * H_ + kk * 32 + kgrp);
    }
  }
  const int cg0 = (int)hid * 32 + (lane & 15);
  const int cg1 = cg0 + 16;
  short* ggx_s = (short*)g_ggx;

  for (int c = 0; c < NCH; ++c) {
    if (tid == 0) {
      int guard = 0;
      while (ld_ag(g_l0prog) < (unsigned)(c * TC + TC)) {
        __builtin_amdgcn_s_sleep(4);
        if (++guard > GUARD) break;
      }
    }
    __syncthreads();
    const int t0 = c * TC;

#pragma unroll 1
    for (int mt = 0; mt < 4; ++mt) {
      const int arow = w * 64 + mt * 16 + (lane & 15);        // 0..255
      const size_t abase = (((size_t)(t0 + (arow >> 5) + 1) * BH) +
                            (size_t)(arow & 31) * H_ + kgrp) >> 2;   // ull units
      f32x4 e0 = {0.f,0.f,0.f,0.f}, e1 = {0.f,0.f,0.f,0.f};
#pragma unroll
      for (int kk = 0; kk < 32; ++kk) {
        union { ull u[2]; half8 v; } a;
        a.u[0] = ld_ag64(&g_y0pub[abase + kk * 8]);
        a.u[1] = ld_ag64(&g_y0pub[abase + kk * 8 + 1]);
        e0 = __builtin_amdgcn_mfma_f32_16x16x32_f16(a.v, wih0[kk], e0, 0, 0, 0);
        e1 = __builtin_amdgcn_mfma_f32_16x16x32_f16(a.v, wih1[kk], e1, 0, 0, 0);
      }
      const int mrow = w * 64 + mt * 16 + (lane >> 4) * 4;
#pragma unroll
      for (int r = 0; r < 4; ++r) {
        const int m = mrow + r;
        const int tt = t0 + (m >> 5);
        const int bb = m & 31;
        const _Float16 v0 = (_Float16)e0[r];    // raw GEMM; bias added by L1
        const _Float16 v1 = (_Float16)e1[r];
        __hip_atomic_store(&ggx_s[((size_t)tt * B_ + bb) * GX + cg0],
                           __builtin_bit_cast(short, v0),
                           __ATOMIC_RELAXED, __HIP_MEMORY_SCOPE_AGENT);
        __hip_atomic_store(&ggx_s[((size_t)tt * B_ + bb) * GX + cg1],
                           __builtin_bit_cast(short, v1),
                           __ATOMIC_RELAXED, __HIP_MEMORY_SCOPE_AGENT);
      }
    }
    __syncthreads();                       // drain sc1 stores
    if (tid == 0) add_ag(&g_chunk[c * 32]);
  }
}

// ---------------------------------------------------------------------------
extern "C" void kernel_launch(void* const* d_in, const int* in_sizes, int n_in,
                              void* d_out, int out_size, void* d_ws, size_t ws_size,
                              hipStream_t stream) {
  (void)in_sizes; (void)n_in; (void)d_ws; (void)ws_size; (void)out_size;

  const int*   x    = (const int*)  d_in[0];
  const float* Hst  = (const float*)d_in[1];
  const float* Cst  = (const float*)d_in[2];
  const float* Wih0 = (const float*)d_in[3];
  const float* Whh0 = (const float*)d_in[4];
  const float* bih0 = (const float*)d_in[5];
  const float* bhh0 = (const float*)d_in[6];
  const float* Wih1 = (const float*)d_in[7];
  const float* Whh1 = (const float*)d_in[8];
  const float* bih1 = (const float*)d_in[9];
  const float* bhh1 = (const float*)d_in[10];

  float* out   = (float*)d_out;
  float* y1out = out;
  float* outh  = out + (size_t)T_ * BH;
  float* outc  = outh + (size_t)2 * BH;

  hipLaunchKernelGGL(init_bar_k, dim3(1), dim3(1024), 0, stream);
  hipLaunchKernelGGL(transpose_wih0, dim3(8192), dim3(256), 0, stream, Wih0);
  hipLaunchKernelGGL(lstm_fused, dim3(256), dim3(TPB), 0, stream,
                     Whh0, bih0, bhh0, Wih1, Whh1, bih1, bhh1,
                     x, Hst, Cst, y1out, outh, outc);
}